// Round 8
// baseline (461.798 us; speedup 1.0000x reference)
//
#include <hip/hip_runtime.h>
#include <math.h>

// DSA sparse attention, MI355X. Round 8 = Round 7 resubmit (bench infra
// timeout, kernel never ran): ILP unlock (__launch_bounds__(256,4)),
// 1-pass select fast path (ballot compaction + u64 max-reduce boundary
// resolve, 3-pass radix fallback), PV batching, XCD swizzle on scores.

#define B_   2
#define S_   4096
#define DM_  1024
#define HQ_  8
#define TK_  256

typedef unsigned int u32;
typedef unsigned long long u64;
typedef unsigned short US;
typedef __attribute__((ext_vector_type(8))) short short8;
typedef __attribute__((ext_vector_type(4))) float f32x4;

__device__ __forceinline__ float dot4(const float4 a, const float4 b) {
    return a.x*b.x + a.y*b.y + a.z*b.z + a.w*b.w;
}
__device__ __forceinline__ u32 fkey(float f) {
    u32 b = __float_as_uint(f);
    return (b & 0x80000000u) ? ~b : (b | 0x80000000u);
}
__device__ __forceinline__ u32 bfbits(float f) {
    const u32 u = __float_as_uint(f);
    return (u + 0x7FFFu + ((u >> 16) & 1u)) >> 16;
}
__device__ __forceinline__ float bfval(u32 bits) {
    return __uint_as_float(bits << 16);
}
__device__ __forceinline__ void split3(float v, US& a, US& b, US& c) {
    const u32 ab = bfbits(v); const float fa = bfval(ab);
    const float r1 = v - fa;
    const u32 bb = bfbits(r1); const float fb = bfval(bb);
    const u32 cb = bfbits(r1 - fb);
    a = (US)ab; b = (US)bb; c = (US)cb;
}
__device__ __forceinline__ u64 shfl_xor_u64(u64 v, int off) {
    const u32 lo = __shfl_xor((u32)v, off);
    const u32 hi = __shfl_xor((u32)(v >> 32), off);
    return ((u64)hi << 32) | (u64)lo;
}

// ---------------- Kernel 0: W -> 3-limb bf16 ----------------
__global__ __launch_bounds__(256) void k_wsplit(
    const float* __restrict__ Wq, const float* __restrict__ Wk,
    US* __restrict__ wl)
{
    const int o   = blockIdx.x;            // 0..127
    const int tid = threadIdx.x;
    const float* src = (o < 64) ? (Wq + (size_t)o*DM_)
                                : (Wk + (size_t)(o-64)*DM_);
    const int k0 = tid * 4;
    const float4 v = *(const float4*)&src[k0];
    float vv[4] = {v.x, v.y, v.z, v.w};
    US aa[4], bb[4], cc[4];
    #pragma unroll
    for (int i = 0; i < 4; ++i) split3(vv[i], aa[i], bb[i], cc[i]);
    const size_t base = (size_t)o*DM_ + k0;
    *(ushort4*)&wl[0*131072 + base] = make_ushort4(aa[0],aa[1],aa[2],aa[3]);
    *(ushort4*)&wl[1*131072 + base] = make_ushort4(bb[0],bb[1],bb[2],bb[3]);
    *(ushort4*)&wl[2*131072 + base] = make_ushort4(cc[0],cc[1],cc[2],cc[3]);
}

// ---------------- Kernel 1: MFMA projection + LN + limb split ---------------
__global__ __launch_bounds__(256, 4) void k_proj_mfma(
    const float* __restrict__ x, const US* __restrict__ wl,
    const float* __restrict__ bq, const float* __restrict__ bk,
    const float* __restrict__ lg, const float* __restrict__ lb,
    US* __restrict__ qa, US* __restrict__ qb, US* __restrict__ qc,
    US* __restrict__ ka, US* __restrict__ kb, US* __restrict__ kc)
{
    __shared__ US xl[3][16][264];
    const int tid   = threadIdx.x;
    const int w     = tid >> 6, lane = tid & 63;
    const int row16 = lane & 15, kblk = lane >> 4;
    const size_t s0 = (size_t)blockIdx.x * 16;

    f32x4 acc0 = {0.f,0.f,0.f,0.f};
    f32x4 acc1 = {0.f,0.f,0.f,0.f};

    const int srow = tid >> 4;
    const int scol = (tid & 15) * 16;

    for (int ck = 0; ck < 4; ++ck) {
        {
            const float* xr = x + (s0 + srow)*DM_ + ck*256 + scol;
            #pragma unroll
            for (int q4 = 0; q4 < 4; ++q4) {
                const float4 v = *(const float4*)(xr + q4*4);
                float vv[4] = {v.x, v.y, v.z, v.w};
                US aa[4], bb[4], cc[4];
                #pragma unroll
                for (int i = 0; i < 4; ++i) split3(vv[i], aa[i], bb[i], cc[i]);
                const int cb = scol + q4*4;
                *(ushort4*)&xl[0][srow][cb] = make_ushort4(aa[0],aa[1],aa[2],aa[3]);
                *(ushort4*)&xl[1][srow][cb] = make_ushort4(bb[0],bb[1],bb[2],bb[3]);
                *(ushort4*)&xl[2][srow][cb] = make_ushort4(cc[0],cc[1],cc[2],cc[3]);
            }
        }
        __syncthreads();
        #pragma unroll
        for (int kt = 0; kt < 8; ++kt) {
            short8 A[3], B0[3], B1[3];
            #pragma unroll
            for (int l = 0; l < 3; ++l)
                A[l] = *(const short8*)&xl[l][row16][kt*32 + kblk*8];
            const size_t wko = (size_t)(ck*256 + kt*32 + kblk*8);
            #pragma unroll
            for (int l = 0; l < 3; ++l) {
                B0[l] = *(const short8*)&wl[(size_t)l*131072 + (size_t)(w*32 +      row16)*DM_ + wko];
                B1[l] = *(const short8*)&wl[(size_t)l*131072 + (size_t)(w*32 + 16 + row16)*DM_ + wko];
            }
            acc0 = __builtin_amdgcn_mfma_f32_16x16x32_bf16(A[1], B0[1], acc0, 0,0,0);
            acc0 = __builtin_amdgcn_mfma_f32_16x16x32_bf16(A[0], B0[2], acc0, 0,0,0);
            acc0 = __builtin_amdgcn_mfma_f32_16x16x32_bf16(A[2], B0[0], acc0, 0,0,0);
            acc0 = __builtin_amdgcn_mfma_f32_16x16x32_bf16(A[0], B0[1], acc0, 0,0,0);
            acc0 = __builtin_amdgcn_mfma_f32_16x16x32_bf16(A[1], B0[0], acc0, 0,0,0);
            acc0 = __builtin_amdgcn_mfma_f32_16x16x32_bf16(A[0], B0[0], acc0, 0,0,0);
            acc1 = __builtin_amdgcn_mfma_f32_16x16x32_bf16(A[1], B1[1], acc1, 0,0,0);
            acc1 = __builtin_amdgcn_mfma_f32_16x16x32_bf16(A[0], B1[2], acc1, 0,0,0);
            acc1 = __builtin_amdgcn_mfma_f32_16x16x32_bf16(A[2], B1[0], acc1, 0,0,0);
            acc1 = __builtin_amdgcn_mfma_f32_16x16x32_bf16(A[0], B1[1], acc1, 0,0,0);
            acc1 = __builtin_amdgcn_mfma_f32_16x16x32_bf16(A[1], B1[0], acc1, 0,0,0);
            acc1 = __builtin_amdgcn_mfma_f32_16x16x32_bf16(A[0], B1[0], acc1, 0,0,0);
        }
        __syncthreads();
    }

    const int c0 = w*32 + row16;
    const int c1 = c0 + 16;
    const float bias0 = (w < 2) ? bq[c0] : bk[c0 - 64];
    const float bias1 = (w < 2) ? bq[c1] : bk[c1 - 64];
    const float gv0 = lg[c0 & 31], bv0 = lb[c0 & 31];
    const float gv1 = lg[c1 & 31], bv1 = lb[c1 & 31];
    US* __restrict__ oa = (w < 2) ? qa : ka;
    US* __restrict__ ob = (w < 2) ? qb : kb;
    US* __restrict__ oc = (w < 2) ? qc : kc;
    const int oc0 = c0 & 63, oc1 = c1 & 63;

    #pragma unroll
    for (int r = 0; r < 4; ++r) {
        const float v0 = acc0[r] + bias0;
        const float v1 = acc1[r] + bias1;
        float s1 = v0 + v1;
        float s2 = v0*v0 + v1*v1;
        #pragma unroll
        for (int off = 1; off < 16; off <<= 1) {
            s1 += __shfl_xor(s1, off);
            s2 += __shfl_xor(s2, off);
        }
        const float m   = s1 * (1.f/32.f);
        const float var = fmaxf(s2 * (1.f/32.f) - m*m, 0.f);
        const float inv = rsqrtf(var + 1e-5f);
        const float o0 = (v0 - m)*inv*gv0 + bv0;
        const float o1 = (v1 - m)*inv*gv1 + bv1;
        const size_t grow = s0 + (size_t)kblk*4 + r;
        US a0,b0,cl0, a1,b1,cl1;
        split3(o0, a0, b0, cl0);
        split3(o1, a1, b1, cl1);
        oa[grow*64 + oc0] = a0; ob[grow*64 + oc0] = b0; oc[grow*64 + oc0] = cl0;
        oa[grow*64 + oc1] = a1; ob[grow*64 + oc1] = b1; oc[grow*64 + oc1] = cl1;
    }
}

// ---------------- Kernel 2: MFMA score GEMM -> global keys ----------------
// 1D grid 8192 with bijective XCD swizzle: same-s-panel blocks co-locate.
__global__ __launch_bounds__(256, 4) void k_scores_mfma(
    const US* __restrict__ qa, const US* __restrict__ qb, const US* __restrict__ qc,
    const US* __restrict__ ka, const US* __restrict__ kb, const US* __restrict__ kc,
    const float* __restrict__ idxw, u32* __restrict__ keys)
{
    const int tid  = threadIdx.x;
    const int w    = tid >> 6, lane = tid & 63;
    const int row16 = lane & 15, kblk = lane >> 4;
    const u32 flat = blockIdx.x;
    const int j    = (int)(flat >> 3);
    const int by   = (int)(flat & 7)*16 + (j & 15);  // 0..127
    const int bx   = j >> 4;                         // 0..63
    const int b    = by >> 6;
    const int sB   = (by & 63)*64 + (w >> 1)*32;
    const int tB   = bx*64 + (w & 1)*32;
    const float w0 = idxw[0], w1 = idxw[1];

    const US* kL[3] = { ka, kb, kc };
    const US* qL[3] = { qa, qb, qc };

    const size_t sOff = ((size_t)b*S_ + sB + row16)*64 + (size_t)kblk*8;
    const size_t tOff = ((size_t)b*S_ + tB + row16)*64 + (size_t)kblk*8;

    short8 A[2][2][3], Bv[2][2][3];
    #pragma unroll
    for (int st = 0; st < 2; ++st)
        #pragma unroll
        for (int h = 0; h < 2; ++h)
            #pragma unroll
            for (int l = 0; l < 3; ++l) {
                A[st][h][l]  = *(const short8*)(kL[l] + sOff + st*1024 + h*32);
                Bv[st][h][l] = *(const short8*)(qL[l] + tOff + st*1024 + h*32);
            }

    #pragma unroll
    for (int st = 0; st < 2; ++st) {
        #pragma unroll
        for (int tt = 0; tt < 2; ++tt) {
            f32x4 acc[2];
            #pragma unroll
            for (int h = 0; h < 2; ++h) {
                f32x4 c = {0.f, 0.f, 0.f, 0.f};
                c = __builtin_amdgcn_mfma_f32_16x16x32_bf16(A[st][h][1], Bv[tt][h][1], c, 0,0,0);
                c = __builtin_amdgcn_mfma_f32_16x16x32_bf16(A[st][h][0], Bv[tt][h][2], c, 0,0,0);
                c = __builtin_amdgcn_mfma_f32_16x16x32_bf16(A[st][h][2], Bv[tt][h][0], c, 0,0,0);
                c = __builtin_amdgcn_mfma_f32_16x16x32_bf16(A[st][h][0], Bv[tt][h][1], c, 0,0,0);
                c = __builtin_amdgcn_mfma_f32_16x16x32_bf16(A[st][h][1], Bv[tt][h][0], c, 0,0,0);
                c = __builtin_amdgcn_mfma_f32_16x16x32_bf16(A[st][h][0], Bv[tt][h][0], c, 0,0,0);
                acc[h] = c;
            }
            u32* kout = keys + ((size_t)b*S_ + sB + st*16 + kblk*4)*S_
                             + tB + tt*16 + row16;
            #pragma unroll
            for (int r = 0; r < 4; ++r) {
                const float sc = w0*fmaxf(acc[0][r], 0.f) + w1*fmaxf(acc[1][r], 0.f);
                kout[(size_t)r*S_] = fkey(sc);
            }
        }
    }
}

// ---------------- Kernel 3: fused top-256 select + gathered attention ------
__global__ __launch_bounds__(256, 4) void k_sel_attn(
    const u32* __restrict__ keys,
    const float* __restrict__ Q, const float* __restrict__ K,
    const float* __restrict__ V, float* __restrict__ out)
{
    __shared__ __align__(16) char smemraw[20480];  // kly 16K | hist 4K (reused)
    __shared__ int  il[256];
    __shared__ u64  blist[64];
    __shared__ u32  wcnt[8];
    __shared__ u32  cnts[4];
    __shared__ float MZ[16];

    u32* kly  = (u32*)smemraw;
    u32* hist = (u32*)(smemraw + 16384);

    const int tid = threadIdx.x, lane = tid & 63, w = tid >> 6;
    const size_t row = blockIdx.x;
    const int b = (int)(row >> 12);
    const int s = (int)(row & 4095);

    // ---- clear + stage + fused byte-0 histogram ----
    ((uint4*)hist)[tid] = make_uint4(0u,0u,0u,0u);
    if (tid < 4) cnts[tid] = 0u;
    __syncthreads();
    {
        const u32* krow = keys + row * S_;
        #pragma unroll
        for (int i = 0; i < 4; ++i) {
            const uint4 kk4 = ((const uint4*)krow)[tid + i*256];
            ((uint4*)kly)[tid + i*256] = kk4;
            atomicAdd(&hist[(w<<8) | (kk4.x >> 24)], 1u);
            atomicAdd(&hist[(w<<8) | (kk4.y >> 24)], 1u);
            atomicAdd(&hist[(w<<8) | (kk4.z >> 24)], 1u);
            atomicAdd(&hist[(w<<8) | (kk4.w >> 24)], 1u);
        }
    }
    __syncthreads();

    // ---- scan: pick boundary byte b0; krem1 to take from it; nb = bin count
    u32 b0, krem1, nb;
    {
        const uint4 t0 = ((const uint4*)(hist      ))[lane];
        const uint4 t1 = ((const uint4*)(hist + 256))[lane];
        const uint4 t2 = ((const uint4*)(hist + 512))[lane];
        const uint4 t3 = ((const uint4*)(hist + 768))[lane];
        uint4 h4;
        h4.x = t0.x + t1.x + t2.x + t3.x;
        h4.y = t0.y + t1.y + t2.y + t3.y;
        h4.z = t0.z + t1.z + t2.z + t3.z;
        h4.w = t0.w + t1.w + t2.w + t3.w;
        u32 ssum = h4.x + h4.y + h4.z + h4.w;
        #pragma unroll
        for (int off = 1; off < 64; off <<= 1) {
            const u32 tt = __shfl_down(ssum, off);
            if (lane + off < 64) ssum += tt;
        }
        u32 up = __shfl_down(ssum, 1);
        if (lane == 63) up = 0;
        const u32 a3 = up;
        const u32 a2 = a3 + h4.w;
        const u32 a1 = a2 + h4.z;
        const u32 a0 = a1 + h4.y;
        u32 binl = 0, nkl = 0, cbl = 0; bool hit = false;
        if      (a0 < TK_ && a0 + h4.x >= TK_) { hit = true; binl = 4*lane+0; nkl = TK_ - a0; cbl = h4.x; }
        else if (a1 < TK_ && a1 + h4.y >= TK_) { hit = true; binl = 4*lane+1; nkl = TK_ - a1; cbl = h4.y; }
        else if (a2 < TK_ && a2 + h4.z >= TK_) { hit = true; binl = 4*lane+2; nkl = TK_ - a2; cbl = h4.z; }
        else if (a3 < TK_ && a3 + h4.w >= TK_) { hit = true; binl = 4*lane+3; nkl = TK_ - a3; cbl = h4.w; }
        const u64 mball = __ballot(hit);
        const int src = __ffsll((long long)mball) - 1;
        b0    = __shfl(binl, src);
        krem1 = __shfl(nkl, src);
        nb    = __shfl(cbl, src);
    }

    const int G0 = TK_ - (int)krem1;
    const u64 lmask = lane ? ((~0ull) >> (64 - lane)) : 0ull;

    if (nb <= 64u) {
        // ---- FAST: one sweep, ballot-compact; boundary resolved by u64 max
        #pragma unroll 4
        for (int i = 0; i < 16; ++i) {
            const int idx = (w<<10) + (i<<6) + lane;
            const u32 kk = kly[idx];
            const u32 hb = kk >> 24;
            const bool isgt = hb > b0;
            const bool isbd = (hb == b0);
            const u64 mgt = __ballot(isgt);
            const u64 mbd = __ballot(isbd);
            u32 bgt = 0, bbd = 0;
            if (lane == 0) {
                if (mgt) bgt = atomicAdd(&cnts[0], (u32)__popcll(mgt));
                if (mbd) bbd = atomicAdd(&cnts[1], (u32)__popcll(mbd));
            }
            bgt = __shfl(bgt, 0); bbd = __shfl(bbd, 0);
            if (isgt) il[bgt + __popcll(mgt & lmask)] = idx;
            if (isbd) blist[bbd + __popcll(mbd & lmask)] =
                ((u64)kk << 12) | (u64)(4095 - idx);
        }
        __syncthreads();
        if (w == 0) {
            u64 v = (lane < (int)nb) ? blist[lane] : 0ull;
            for (int t2 = 0; t2 < (int)krem1; ++t2) {
                u64 m = v;
                #pragma unroll
                for (int off = 32; off >= 1; off >>= 1) {
                    const u64 o = shfl_xor_u64(m, off);
                    if (o > m) m = o;
                }
                if (v == m) { il[G0 + t2] = 4095 - (int)(m & 0xFFFull); v = 0ull; }
            }
        }
    } else {
        // ---- SLOW: radix passes 1..3 + full compaction (R6-verified path)
        u32 prefix = b0; u32 krem = krem1;
        #pragma unroll 1
        for (int pass = 1; pass < 4; ++pass) {
            const int shift = 24 - 8*pass;
            __syncthreads();
            ((uint4*)hist)[tid] = make_uint4(0u,0u,0u,0u);
            __syncthreads();
            #pragma unroll
            for (int i = 0; i < 16; ++i) {
                const u32 kk = kly[tid + i*256];
                const bool ok = ((kk >> (shift+8)) == prefix);
                if (ok) atomicAdd(&hist[(w<<8) | ((kk >> shift) & 255)], 1u);
            }
            __syncthreads();
            const uint4 t0 = ((const uint4*)(hist      ))[lane];
            const uint4 t1 = ((const uint4*)(hist + 256))[lane];
            const uint4 t2 = ((const uint4*)(hist + 512))[lane];
            const uint4 t3 = ((const uint4*)(hist + 768))[lane];
            uint4 h4;
            h4.x = t0.x + t1.x + t2.x + t3.x;
            h4.y = t0.y + t1.y + t2.y + t3.y;
            h4.z = t0.z + t1.z + t2.z + t3.z;
            h4.w = t0.w + t1.w + t2.w + t3.w;
            u32 ssum = h4.x + h4.y + h4.z + h4.w;
            #pragma unroll
            for (int off = 1; off < 64; off <<= 1) {
                const u32 tt = __shfl_down(ssum, off);
                if (lane + off < 64) ssum += tt;
            }
            u32 up = __shfl_down(ssum, 1);
            if (lane == 63) up = 0;
            const u32 a3 = up;
            const u32 a2 = a3 + h4.w;
            const u32 a1 = a2 + h4.z;
            const u32 a0 = a1 + h4.y;
            u32 binl = 0, nkl = 0; bool hit = false;
            if      (a0 < krem && a0 + h4.x >= krem) { hit = true; binl = 4*lane+0; nkl = krem - a0; }
            else if (a1 < krem && a1 + h4.y >= krem) { hit = true; binl = 4*lane+1; nkl = krem - a1; }
            else if (a2 < krem && a2 + h4.z >= krem) { hit = true; binl = 4*lane+2; nkl = krem - a2; }
            else if (a3 < krem && a3 + h4.w >= krem) { hit = true; binl = 4*lane+3; nkl = krem - a3; }
            const u64 mball = __ballot(hit);
            const int src = __ffsll((long long)mball) - 1;
            const u32 bsel = __shfl(binl, src);
            krem = __shfl(nkl, src);
            prefix = (prefix << 8) | bsel;
        }
        __syncthreads();
        const u32 T = prefix;
        const int G = TK_ - (int)krem;
        int cgt = 0, ceq = 0;
        #pragma unroll
        for (int i = 0; i < 16; ++i) {
            const u32 kk = kly[(w<<10) + (i<<6) + lane];
            cgt += __popcll(__ballot(kk > T));
            ceq += __popcll(__ballot(kk == T));
        }
        if (lane == 0) { wcnt[w] = (u32)cgt; wcnt[4 + w] = (u32)ceq; }
        __syncthreads();
        int gts = 0, eqs = 0;
        for (int w2 = 0; w2 < 4; ++w2)
            if (w2 < w) { gts += (int)wcnt[w2]; eqs += (int)wcnt[4 + w2]; }
        cgt = gts; ceq = eqs;
        #pragma unroll
        for (int i = 0; i < 16; ++i) {
            const int idx = (w<<10) + (i<<6) + lane;
            const u32 kk = kly[idx];
            const bool gt = kk > T, eq = (kk == T);
            const u64 mgt = __ballot(gt), meq = __ballot(eq);
            if (gt) il[cgt + __popcll(mgt & lmask)] = idx;
            if (eq) {
                const int rk = ceq + __popcll(meq & lmask);
                if (rk < (int)krem) il[G + rk] = idx;
            }
            cgt += __popcll(mgt); ceq += __popcll(meq);
        }
    }
    __syncthreads();   // il complete; kly/hist regions free for attn

    // ---- phase 2: attention ----
    float* qsm   = (float*)smemraw;          // 512 f
    float* wmat  = qsm + 512;                // 2048 f
    float* opart = qsm + 2560;               // 2048 f

    qsm[tid]     = Q[((size_t)(b*HQ_ + (tid>>6)))*S_*64 + (size_t)s*64 + (tid&63)];
    qsm[256+tid] = Q[((size_t)(b*HQ_ + 4 + (tid>>6)))*S_*64 + (size_t)s*64 + (tid&63)];
    __syncthreads();

    const float* kp = K + ((size_t)(b*S_ + il[tid]))*64;
    float4 kx[16];
    #pragma unroll
    for (int g = 0; g < 16; ++g) kx[g] = *(const float4*)(kp + g*4);
    float sc[8];
    #pragma unroll
    for (int h = 0; h < 8; ++h) {
        float a = 0.f;
        #pragma unroll
        for (int g = 0; g < 16; ++g)
            a += dot4(*(const float4*)&qsm[h*64 + g*4], kx[g]);
        sc[h] = a * 0.125f;
    }
    #pragma unroll
    for (int h = 0; h < 8; ++h) wmat[h*256 + tid] = sc[h];
    __syncthreads();

    #pragma unroll
    for (int hh = 0; hh < 2; ++hh) {
        const int h = hh*4 + w;
        const float4 v4 = *(const float4*)&wmat[h*256 + lane*4];
        float mm = fmaxf(fmaxf(v4.x, v4.y), fmaxf(v4.z, v4.w));
        #pragma unroll
        for (int off = 32; off >= 1; off >>= 1) mm = fmaxf(mm, __shfl_xor(mm, off));
        if (lane == 0) MZ[h] = mm;
    }
    __syncthreads();
    #pragma unroll
    for (int h = 0; h < 8; ++h) wmat[h*256 + tid] = __expf(sc[h] - MZ[h]);
    __syncthreads();
    #pragma unroll
    for (int hh = 0; hh < 2; ++hh) {
        const int h = hh*4 + w;
        const float4 v4 = *(const float4*)&wmat[h*256 + lane*4];
        float ss = v4.x + v4.y + v4.z + v4.w;
        #pragma unroll
        for (int off = 32; off >= 1; off >>= 1) ss += __shfl_xor(ss, off);
        if (lane == 0) MZ[8 + h] = ss;
    }
    __syncthreads();

    // ---- PV with batched prefetch (8 gathered float4 in flight) ----
    const int dq = lane & 15, jsub = lane >> 4;
    float4 p[8];
    #pragma unroll
    for (int h = 0; h < 8; ++h) p[h] = make_float4(0.f,0.f,0.f,0.f);
    #pragma unroll
    for (int ii = 0; ii < 2; ++ii) {
        float4 vbuf[8];
        #pragma unroll
        for (int i = 0; i < 8; ++i) {
            const int j = w*64 + jsub*16 + ii*8 + i;
            vbuf[i] = *(const float4*)&V[((size_t)(b*S_ + il[j]))*64 + dq*4];
        }
        #pragma unroll
        for (int i = 0; i < 8; ++i) {
            const int j = w*64 + jsub*16 + ii*8 + i;
            #pragma unroll
            for (int h = 0; h < 8; ++h) {
                const float wv = wmat[h*256 + j];
                p[h].x += wv*vbuf[i].x; p[h].y += wv*vbuf[i].y;
                p[h].z += wv*vbuf[i].z; p[h].w += wv*vbuf[i].w;
            }
        }
    }
    #pragma unroll
    for (int h = 0; h < 8; ++h) {
        p[h].x += __shfl_xor(p[h].x, 16); p[h].y += __shfl_xor(p[h].y, 16);
        p[h].z += __shfl_xor(p[h].z, 16); p[h].w += __shfl_xor(p[h].w, 16);
        p[h].x += __shfl_xor(p[h].x, 32); p[h].y += __shfl_xor(p[h].y, 32);
        p[h].z += __shfl_xor(p[h].z, 32); p[h].w += __shfl_xor(p[h].w, 32);
    }
    if (jsub == 0) {
        #pragma unroll
        for (int h = 0; h < 8; ++h)
            *(float4*)&opart[(w*8 + h)*64 + dq*4] = p[h];
    }
    __syncthreads();
    {
        const int h = tid >> 5, d0 = (tid & 31) * 2;
        float o0 = 0.f, o1 = 0.f;
        #pragma unroll
        for (int g = 0; g < 4; ++g) {
            o0 += opart[(g*8 + h)*64 + d0];
            o1 += opart[(g*8 + h)*64 + d0 + 1];
        }
        const float iz = 1.f / MZ[8 + h];
        *(float2*)&out[((size_t)(b*S_ + s))*512 + h*64 + d0] =
            make_float2(o0*iz, o1*iz);
    }
}

// ---------------- launcher ----------------
extern "C" void kernel_launch(void* const* d_in, const int* in_sizes, int n_in,
                              void* d_out, int out_size, void* d_ws, size_t ws_size,
                              hipStream_t stream) {
    const float* x  = (const float*)d_in[0];
    const float* Q  = (const float*)d_in[1];
    const float* K  = (const float*)d_in[2];
    const float* V  = (const float*)d_in[3];
    const float* Wq = (const float*)d_in[4];
    const float* bq = (const float*)d_in[5];
    const float* Wk = (const float*)d_in[6];
    const float* bk = (const float*)d_in[7];
    const float* lg = (const float*)d_in[8];
    const float* lb = (const float*)d_in[9];
    const float* iw = (const float*)d_in[10];
    float* out = (float*)d_out;

    char* ws = (char*)d_ws;
    US*   wl  = (US*)ws;                        // 768 KB
    US*   qa  = (US*)(ws + ( 1u<<20));          // 1 MB each
    US*   qb  = (US*)(ws + ( 2u<<20));
    US*   qc  = (US*)(ws + ( 3u<<20));
    US*   ka  = (US*)(ws + ( 4u<<20));
    US*   kb  = (US*)(ws + ( 5u<<20));
    US*   kc  = (US*)(ws + ( 6u<<20));
    u32* keys = (u32*)(ws + (16u<<20));         // 128 MB

    (void)in_sizes; (void)n_in; (void)out_size; (void)ws_size;

    k_wsplit<<<dim3(128), dim3(256), 0, stream>>>(Wq, Wk, wl);
    k_proj_mfma<<<dim3((B_*S_)/16), dim3(256), 0, stream>>>(
        x, wl, bq, bk, lg, lb, qa, qb, qc, ka, kb, kc);
    k_scores_mfma<<<dim3(8192), dim3(256), 0, stream>>>(
        qa, qb, qc, ka, kb, kc, iw, keys);
    k_sel_attn<<<dim3(B_*S_), dim3(256), 0, stream>>>(
        keys, Q, K, V, out);
}